// Round 7
// baseline (338.381 us; speedup 1.0000x reference)
//
#include <hip/hip_runtime.h>
#include <cstdint>
#include <cmath>

typedef __bf16 bf16x8 __attribute__((ext_vector_type(8)));
typedef float  f32x4  __attribute__((ext_vector_type(4)));

#define DEVI __device__ __forceinline__

#define SEQ 4096
#define NH 8
#define NKV 4
#define HD 256
#define WIN 1024

DEVI void gload16(const void* g, void* l) {
  __builtin_amdgcn_global_load_lds((const __attribute__((address_space(1))) void*)g,
                                   (__attribute__((address_space(3))) void*)l,
                                   16, 0, 0);
}

DEVI bf16x8 ld8f(const float* p) {
  const f32x4 a = *(const f32x4*)p;
  const f32x4 b = *(const f32x4*)(p + 4);
  bf16x8 r;
#pragma unroll
  for (int j = 0; j < 4; ++j) { r[j] = (__bf16)a[j]; r[4 + j] = (__bf16)b[j]; }
  return r;
}

DEVI void st1(float* p, float v)  { *p = v; }
DEVI void st1(__bf16* p, float v) { *p = (__bf16)v; }

// ---------------------------------------------------------------------------
// fp32 -> bf16 conversion. Wq/Wk/Wv concatenated into one 4096x2048 buffer.
// ---------------------------------------------------------------------------
__global__ __launch_bounds__(256)
void cvt_all(const float* __restrict__ x,  const float* __restrict__ wq,
             const float* __restrict__ wk, const float* __restrict__ wv,
             const float* __restrict__ wo,
             __bf16* __restrict__ xb, __bf16* __restrict__ wqkvb,
             __bf16* __restrict__ wob) {
  const size_t g = (size_t)blockIdx.x * 256 + threadIdx.x;
  const float* src; __bf16* dst; size_t off;
  if      (g < 1048576) { src = x;  dst = xb;               off = g; }
  else if (g < 1572864) { src = wq; dst = wqkvb;            off = g - 1048576; }
  else if (g < 1835008) { src = wk; dst = wqkvb + 4194304;  off = g - 1572864; }
  else if (g < 2097152) { src = wv; dst = wqkvb + 6291456;  off = g - 1835008; }
  else                  { src = wo; dst = wob;              off = g - 2097152; }
  *(bf16x8*)(dst + off * 8) = ld8f(src + off * 8);
}

// ---------------------------------------------------------------------------
// m97-style GEMM: C[M][N] = A[M][K] * B[N][K]^T, bf16 in, f32 acc.
// 128x128 tile, BK=32, global_load_lds width-16 staging.
// ---------------------------------------------------------------------------
template <typename TC>
__global__ __launch_bounds__(256, 2)
void gemm_bt(const __bf16* __restrict__ A, const __bf16* __restrict__ B,
             TC* __restrict__ C, int N, int K) {
  __shared__ __bf16 As[128 * 32];
  __shared__ __bf16 Bs[128 * 32];
  const int tid  = threadIdx.x;
  const int lane = tid & 63;
  const int wave = tid >> 6;
  const int l15  = lane & 15;
  const int l4   = lane >> 4;

  const int lin  = blockIdx.x + gridDim.x * blockIdx.y;
  const int xcd  = lin & 7;
  const int kk   = lin >> 3;
  const int row0 = (xcd * 4 + (kk & 3)) * 128;
  const int col0 = (kk >> 2) * 128;

  const int wm   = (wave >> 1) * 64;
  const int wn   = (wave & 1) * 64;

  f32x4 acc[4][4] = {};
  const int r0 = tid >> 2;
  const int c0 = (tid & 3) * 8;

  for (int k0 = 0; k0 < K; k0 += 32) {
    __syncthreads();
    gload16(A + (size_t)(row0 + r0) * K + k0 + c0,      &As[(wave * 64) * 8]);
    gload16(A + (size_t)(row0 + 64 + r0) * K + k0 + c0, &As[(256 + wave * 64) * 8]);
    gload16(B + (size_t)(col0 + r0) * K + k0 + c0,      &Bs[(wave * 64) * 8]);
    gload16(B + (size_t)(col0 + 64 + r0) * K + k0 + c0, &Bs[(256 + wave * 64) * 8]);
    __syncthreads();
    bf16x8 af[4], bfr[4];
#pragma unroll
    for (int i = 0; i < 4; ++i)
      af[i] = *(const bf16x8*)&As[(wm + i * 16 + l15) * 32 + l4 * 8];
#pragma unroll
    for (int i = 0; i < 4; ++i)
      bfr[i] = *(const bf16x8*)&Bs[(wn + i * 16 + l15) * 32 + l4 * 8];
#pragma unroll
    for (int i = 0; i < 4; ++i)
#pragma unroll
      for (int j = 0; j < 4; ++j)
        acc[i][j] = __builtin_amdgcn_mfma_f32_16x16x32_bf16(af[i], bfr[j], acc[i][j], 0, 0, 0);
  }

  // C/D layout: col = lane&15, row = (lane>>4)*4 + reg   [m89/m91 verified]
#pragma unroll
  for (int i = 0; i < 4; ++i) {
#pragma unroll
    for (int reg = 0; reg < 4; ++reg) {
      const int row = row0 + wm + i * 16 + l4 * 4 + reg;
      TC* crow = C + (size_t)row * N + col0 + wn + l15;
#pragma unroll
      for (int j = 0; j < 4; ++j)
        st1(crow + j * 16, acc[i][j][reg]);
    }
  }
}

// ---------------------------------------------------------------------------
// Merged: per-head RMSNorm+RoPE (blocks 0..12287) and V-transpose (12288+).
// Disjoint qkv regions: norm touches cols 0..3071 in place; transpose reads
// cols 3072..4095. Branch is block-uniform.
// ---------------------------------------------------------------------------
__global__ __launch_bounds__(256)
void norm_rope_tv(__bf16* __restrict__ qkv, __bf16* __restrict__ Vt,
                  const float* __restrict__ qw, const float* __restrict__ kw,
                  const int* __restrict__ pos) {
  if (blockIdx.x < 12288) {
    const int gw   = blockIdx.x * 4 + (threadIdx.x >> 6);
    const int lane = threadIdx.x & 63;
    __bf16* base; const float* w; int t;
    if (gw < SEQ * NH) {
      t = gw >> 3;
      base = qkv + (size_t)t * 4096 + (gw & 7) * HD;
      w = qw;
    } else {
      const int g = gw - SEQ * NH;
      t = g >> 2;
      base = qkv + (size_t)t * 4096 + 2048 + (g & 3) * HD;
      w = kw;
    }

    const int d0 = lane * 4;
    float v[4]; float ss = 0.f;
#pragma unroll
    for (int j = 0; j < 4; ++j) { v[j] = (float)base[d0 + j]; ss += v[j] * v[j]; }
#pragma unroll
    for (int off = 1; off < 64; off <<= 1) ss += __shfl_xor(ss, off);
    const float rms = rsqrtf(ss * (1.0f / 256.0f) + 1e-6f);
    const float p = (float)pos[t];

    float n[4];
#pragma unroll
    for (int j = 0; j < 4; ++j) n[j] = v[j] * rms * w[d0 + j];

    float outv[4];
#pragma unroll
    for (int e = 0; e < 4; e += 2) {
      const int i0 = d0 + e, i1 = i0 + 1;
      const float f0 = exp2f(-(float)(i0 & 127) * 0.103810253f);
      const float f1 = exp2f(-(float)(i1 & 127) * 0.103810253f);
      float s0, cc0, s1, cc1;
      sincosf(p * f0, &s0, &cc0);
      sincosf(p * f1, &s1, &cc1);
      outv[e]     = n[e] * cc0 - n[e + 1] * s0;
      outv[e + 1] = n[e + 1] * cc1 + n[e] * s1;
    }
#pragma unroll
    for (int j = 0; j < 4; ++j) base[d0 + j] = (__bf16)outv[j];
  } else {
    __shared__ __bf16 tile[64][72];
    const int b   = blockIdx.x - 12288;       // 0..1023
    const int tid = threadIdx.x;
    const int tb  = (b & 63) * 64;
    const int yy  = b >> 6;                   // 0..15
    const int kvh = yy >> 2;
    const int db  = (yy & 3) * 64;
#pragma unroll
    for (int i = 0; i < 2; ++i) {
      const int s = i * 256 + tid;
      const int r = s >> 3, c = (s & 7) * 8;
      bf16x8 val = *(const bf16x8*)(qkv + (size_t)(tb + r) * 4096 + 3072 + kvh * HD + db + c);
#pragma unroll
      for (int j = 0; j < 8; ++j) tile[r][c + j] = val[j];
    }
    __syncthreads();
#pragma unroll
    for (int i = 0; i < 2; ++i) {
      const int s = i * 256 + tid;
      const int r = s >> 3, c = (s & 7) * 8;
      bf16x8 outv;
#pragma unroll
      for (int j = 0; j < 8; ++j) outv[j] = tile[c + j][r];
      *(bf16x8*)(Vt + (size_t)(kvh * HD + db + r) * SEQ + tb + c) = outv;
    }
  }
}

// ---------------------------------------------------------------------------
// Sliding-window flash attention, fixed-max softmax, TRUE double-buffered
// async K/V staging (one barrier per tile; loads stay in flight across the
// whole compute phase). 512 threads = 8 waves: waves 0-3 -> head 2*kvh,
// waves 4-7 -> head 2*kvh+1 (shared K/V staging). Grid (64 q-tiles, 4 kvh)
// = 256 blocks = 1/CU. LDS 146 KB (2x32KB K, 2x32KB V, 18KB P).
// ---------------------------------------------------------------------------
__global__ __launch_bounds__(512, 2)
void attn_fwd(const __bf16* __restrict__ qkv, const __bf16* __restrict__ Vt,
              __bf16* __restrict__ Y) {
  __shared__ __bf16 Ks2[2][8][64][32];    // 65536 B [buf][k-chunk][key][dim8]
  __shared__ __bf16 Vts2[2][2][256][32];  // 65536 B [buf][key-chunk][dim][key8]
  __shared__ __bf16 Ps[8][16][72];        // 18432 B per-wave P
  const int tid  = threadIdx.x;           // 0..511
  const int lane = tid & 63;
  const int wave = tid >> 6;              // 0..7
  const int l15  = lane & 15;
  const int l4   = lane >> 4;
  const int q0   = blockIdx.x * 64;
  const int kvh  = blockIdx.y;            // 0..3
  const int head = kvh * 2 + (wave >> 2);
  const int qw   = q0 + (wave & 3) * 16;

  // stage one 64-key tile (K: 2048 slots, V: 2048 slots; 4+4 per thread)
  auto stage = [&](int kb, int buf) {
#pragma unroll
    for (int i = 0; i < 4; ++i) {
      const int s = i * 512 + tid;
      gload16(qkv + (size_t)(kb + ((s >> 2) & 63)) * 4096 + 2048 + kvh * HD
                  + (s >> 8) * 32 + (s & 3) * 8,
              (char*)Ks2[buf] + (i * 512 + wave * 64) * 16);
    }
#pragma unroll
    for (int i = 0; i < 4; ++i) {
      const int s = i * 512 + tid;
      gload16(Vt + ((size_t)kvh * HD + ((s >> 2) & 255)) * SEQ + kb
                 + (s >> 10) * 32 + (s & 3) * 8,
              (char*)Vts2[buf] + (i * 512 + wave * 64) * 16);
    }
  };

  // Q fragments: A[m=lane&15][k=(lane>>4)*8+j]; pre-scale 1/16 (exact pow2)
  bf16x8 qf[8];
  const __bf16* qrow = qkv + (size_t)(qw + l15) * 4096 + head * HD;
#pragma unroll
  for (int ks = 0; ks < 8; ++ks) {
    bf16x8 t = *(const bf16x8*)(qrow + ks * 32 + l4 * 8);
#pragma unroll
    for (int j = 0; j < 8; ++j) t[j] = (__bf16)((float)t[j] * 0.0625f);
    qf[ks] = t;
  }

  f32x4 o[16] = {};
  float l_run[4] = {0.f, 0.f, 0.f, 0.f};

  int lo = q0 - (WIN - 1); if (lo < 0) lo = 0;
  const int kt0 = lo >> 6;
  const int kt1 = (q0 + 63) >> 6;   // uniform across the block

  stage(kt0 * 64, kt0 & 1);         // prologue prefetch

  for (int kt = kt0; kt <= kt1; ++kt) {
    const int kb  = kt * 64;
    const int buf = kt & 1;
    __syncthreads();   // tile kt landed (issued a full iter ago); prior reads
                       // of buf^1 finished -> safe to overwrite it below
    if (kt < kt1) stage(kb + 64, buf ^ 1);   // async, in flight all compute

    // S = (Q/16) K^T
    f32x4 s_acc[4] = {};
#pragma unroll
    for (int kn = 0; kn < 4; ++kn) {
#pragma unroll
      for (int ks = 0; ks < 8; ++ks) {
        bf16x8 kf = *(const bf16x8*)&Ks2[buf][ks][kn * 16 + l15][l4 * 8];
        s_acc[kn] = __builtin_amdgcn_mfma_f32_16x16x32_bf16(qf[ks], kf, s_acc[kn], 0, 0, 0);
      }
    }

    // fixed-max softmax: p = exp(min(s,34)-34); masked -> 0
    // (post-RMSNorm |q|=|k|=16, RoPE growth <= sqrt2 => s <= 32 provably)
#pragma unroll
    for (int reg = 0; reg < 4; ++reg) {
      const int r  = l4 * 4 + reg;
      const int qg = qw + r;
      float ps = 0.f;
#pragma unroll
      for (int kn = 0; kn < 4; ++kn) {
        const int kg = kb + kn * 16 + l15;
        const bool ok = (kg <= qg) && (kg > qg - WIN);
        const float p = ok ? __expf(fminf(s_acc[kn][reg], 34.f) - 34.f) : 0.f;
        ps += p;
        Ps[wave][r][kn * 16 + l15] = (__bf16)p;
      }
      l_run[reg] += ps;   // per-lane partial; cross-lane reduce in epilogue
    }

    // O += P V   (Ps per-wave; intra-wave LDS ordering needs no barrier)
#pragma unroll
    for (int ks2 = 0; ks2 < 2; ++ks2) {
      bf16x8 pf = *(const bf16x8*)&Ps[wave][l15][ks2 * 32 + l4 * 8];
#pragma unroll
      for (int dn = 0; dn < 16; ++dn) {
        bf16x8 vf = *(const bf16x8*)&Vts2[buf][ks2][dn * 16 + l15][l4 * 8];
        o[dn] = __builtin_amdgcn_mfma_f32_16x16x32_bf16(pf, vf, o[dn], 0, 0, 0);
      }
    }
  }

  // epilogue: reduce l across the 16 lanes sharing each row, then scale
#pragma unroll
  for (int reg = 0; reg < 4; ++reg) {
#pragma unroll
    for (int off = 1; off < 16; off <<= 1)
      l_run[reg] += __shfl_xor(l_run[reg], off);
    const float inv = 1.0f / l_run[reg];
    const int q = qw + l4 * 4 + reg;
    __bf16* yrow = Y + ((size_t)q * NH + head) * HD + l15;
#pragma unroll
    for (int dn = 0; dn < 16; ++dn)
      yrow[dn * 16] = (__bf16)(o[dn][reg] * inv);
  }
}

// ---------------------------------------------------------------------------
extern "C" void kernel_launch(void* const* d_in, const int* in_sizes, int n_in,
                              void* d_out, int out_size, void* d_ws, size_t ws_size,
                              hipStream_t stream) {
  (void)in_sizes; (void)n_in; (void)out_size; (void)ws_size;
  const float* x   = (const float*)d_in[0];
  const int*   pos = (const int*)d_in[1];
  const float* Wq  = (const float*)d_in[2];
  const float* Wk  = (const float*)d_in[3];
  const float* Wv  = (const float*)d_in[4];
  const float* Wo  = (const float*)d_in[5];
  const float* qw  = (const float*)d_in[6];
  const float* kw  = (const float*)d_in[7];
  float* out = (float*)d_out;

  char* ws = (char*)d_ws;
  const size_t MB = 1024 * 1024;
  __bf16* qkv_ws = (__bf16*)(ws);             // 32 MiB  [4096][4096]
  __bf16* vt_ws  = (__bf16*)(ws + 32 * MB);   //  8 MiB  [4][256][4096]
  __bf16* y_ws   = (__bf16*)(ws + 40 * MB);   // 16 MiB  [4096][2048]
  __bf16* xb     = (__bf16*)(ws + 56 * MB);   // 16 MiB
  __bf16* wqkvb  = (__bf16*)(ws + 72 * MB);   // 16 MiB  [4096][2048]
  __bf16* wob    = (__bf16*)(ws + 88 * MB);   //  8 MiB  (total 96 MiB)

  cvt_all<<<dim3(10240), dim3(256), 0, stream>>>(x, Wq, Wk, Wv, Wo, xb, wqkvb, wob);
  gemm_bt<__bf16><<<dim3(32, 32), dim3(256), 0, stream>>>(xb, wqkvb, qkv_ws, 4096, 2048);
  norm_rope_tv<<<dim3(13312), dim3(256), 0, stream>>>(qkv_ws, vt_ws, qw, kw, pos);
  attn_fwd<<<dim3(64, 4), dim3(512), 0, stream>>>(qkv_ws, vt_ws, y_ws);
  gemm_bt<float><<<dim3(32, 16), dim3(256), 0, stream>>>(y_ws, wob, out, 2048, 2048);
}

// Round 8
// 321.626 us; speedup vs baseline: 1.0521x; 1.0521x over previous
//
#include <hip/hip_runtime.h>
#include <cstdint>
#include <cmath>

typedef __bf16 bf16x8 __attribute__((ext_vector_type(8)));
typedef float  f32x4  __attribute__((ext_vector_type(4)));

#define DEVI __device__ __forceinline__

#define SEQ 4096
#define NH 8
#define NKV 4
#define HD 256
#define WIN 1024

DEVI void gload16(const void* g, void* l) {
  __builtin_amdgcn_global_load_lds((const __attribute__((address_space(1))) void*)g,
                                   (__attribute__((address_space(3))) void*)l,
                                   16, 0, 0);
}

DEVI bf16x8 ld8f(const float* p) {
  const f32x4 a = *(const f32x4*)p;
  const f32x4 b = *(const f32x4*)(p + 4);
  bf16x8 r;
#pragma unroll
  for (int j = 0; j < 4; ++j) { r[j] = (__bf16)a[j]; r[4 + j] = (__bf16)b[j]; }
  return r;
}

DEVI void st1(float* p, float v)  { *p = v; }
DEVI void st1(__bf16* p, float v) { *p = (__bf16)v; }

// ---------------------------------------------------------------------------
// fp32 -> bf16 conversion. Wq/Wk/Wv concatenated into one 4096x2048 buffer.
// ---------------------------------------------------------------------------
__global__ __launch_bounds__(256)
void cvt_all(const float* __restrict__ x,  const float* __restrict__ wq,
             const float* __restrict__ wk, const float* __restrict__ wv,
             const float* __restrict__ wo,
             __bf16* __restrict__ xb, __bf16* __restrict__ wqkvb,
             __bf16* __restrict__ wob) {
  const size_t g = (size_t)blockIdx.x * 256 + threadIdx.x;
  const float* src; __bf16* dst; size_t off;
  if      (g < 1048576) { src = x;  dst = xb;               off = g; }
  else if (g < 1572864) { src = wq; dst = wqkvb;            off = g - 1048576; }
  else if (g < 1835008) { src = wk; dst = wqkvb + 4194304;  off = g - 1572864; }
  else if (g < 2097152) { src = wv; dst = wqkvb + 6291456;  off = g - 1835008; }
  else                  { src = wo; dst = wob;              off = g - 2097152; }
  *(bf16x8*)(dst + off * 8) = ld8f(src + off * 8);
}

// ---------------------------------------------------------------------------
// GEMM: C[M][N] = A[M][K] * B[N][K]^T, bf16 in, f32 acc.
// 128x128 tile, BK=64 with CHUNK-MAJOR LDS (As2[2][128][32]): keeps
// global_load_lds staging exactly linear (slot s*16 == ch*8192+r*64+c4*16)
// AND keeps 64B fragment rows (2-way conflict = free, m136). Halves the
// barrier count vs BK=32 (the m97 ~20% vmcnt(0) drain stall).
// ---------------------------------------------------------------------------
template <typename TC>
__global__ __launch_bounds__(256, 2)
void gemm_bt(const __bf16* __restrict__ A, const __bf16* __restrict__ B,
             TC* __restrict__ C, int N, int K) {
  __shared__ __bf16 As2[2][128][32];   // 16 KB  [k-chunk][row][dim8]
  __shared__ __bf16 Bs2[2][128][32];   // 16 KB
  const int tid  = threadIdx.x;
  const int lane = tid & 63;
  const int wave = tid >> 6;
  const int l15  = lane & 15;
  const int l4   = lane >> 4;

  const int lin  = blockIdx.x + gridDim.x * blockIdx.y;
  const int xcd  = lin & 7;
  const int kk   = lin >> 3;
  const int row0 = (xcd * 4 + (kk & 3)) * 128;
  const int col0 = (kk >> 2) * 128;

  const int wm   = (wave >> 1) * 64;
  const int wn   = (wave & 1) * 64;

  f32x4 acc[4][4] = {};

  for (int k0 = 0; k0 < K; k0 += 64) {
    __syncthreads();
#pragma unroll
    for (int i = 0; i < 4; ++i) {
      const int s  = i * 256 + tid;
      const int ch = s >> 9, r = (s >> 2) & 127, c4 = s & 3;
      gload16(A + (size_t)(row0 + r) * K + k0 + ch * 32 + c4 * 8,
              (char*)As2 + (i * 256 + wave * 64) * 16);
    }
#pragma unroll
    for (int i = 0; i < 4; ++i) {
      const int s  = i * 256 + tid;
      const int ch = s >> 9, r = (s >> 2) & 127, c4 = s & 3;
      gload16(B + (size_t)(col0 + r) * K + k0 + ch * 32 + c4 * 8,
              (char*)Bs2 + (i * 256 + wave * 64) * 16);
    }
    __syncthreads();
#pragma unroll
    for (int ch = 0; ch < 2; ++ch) {
      bf16x8 af[4], bfr[4];
#pragma unroll
      for (int i = 0; i < 4; ++i)
        af[i] = *(const bf16x8*)&As2[ch][wm + i * 16 + l15][l4 * 8];
#pragma unroll
      for (int i = 0; i < 4; ++i)
        bfr[i] = *(const bf16x8*)&Bs2[ch][wn + i * 16 + l15][l4 * 8];
#pragma unroll
      for (int i = 0; i < 4; ++i)
#pragma unroll
        for (int j = 0; j < 4; ++j)
          acc[i][j] = __builtin_amdgcn_mfma_f32_16x16x32_bf16(af[i], bfr[j], acc[i][j], 0, 0, 0);
    }
  }

  // C/D layout: col = lane&15, row = (lane>>4)*4 + reg   [m89/m91 verified]
#pragma unroll
  for (int i = 0; i < 4; ++i) {
#pragma unroll
    for (int reg = 0; reg < 4; ++reg) {
      const int row = row0 + wm + i * 16 + l4 * 4 + reg;
      TC* crow = C + (size_t)row * N + col0 + wn + l15;
#pragma unroll
      for (int j = 0; j < 4; ++j)
        st1(crow + j * 16, acc[i][j][reg]);
    }
  }
}

// ---------------------------------------------------------------------------
// Merged: per-head RMSNorm+RoPE (blocks 0..12287) and V-transpose (12288+).
// ---------------------------------------------------------------------------
__global__ __launch_bounds__(256)
void norm_rope_tv(__bf16* __restrict__ qkv, __bf16* __restrict__ Vt,
                  const float* __restrict__ qw, const float* __restrict__ kw,
                  const int* __restrict__ pos) {
  if (blockIdx.x < 12288) {
    const int gw   = blockIdx.x * 4 + (threadIdx.x >> 6);
    const int lane = threadIdx.x & 63;
    __bf16* base; const float* w; int t;
    if (gw < SEQ * NH) {
      t = gw >> 3;
      base = qkv + (size_t)t * 4096 + (gw & 7) * HD;
      w = qw;
    } else {
      const int g = gw - SEQ * NH;
      t = g >> 2;
      base = qkv + (size_t)t * 4096 + 2048 + (g & 3) * HD;
      w = kw;
    }

    const int d0 = lane * 4;
    float v[4]; float ss = 0.f;
#pragma unroll
    for (int j = 0; j < 4; ++j) { v[j] = (float)base[d0 + j]; ss += v[j] * v[j]; }
#pragma unroll
    for (int off = 1; off < 64; off <<= 1) ss += __shfl_xor(ss, off);
    const float rms = rsqrtf(ss * (1.0f / 256.0f) + 1e-6f);
    const float p = (float)pos[t];

    float n[4];
#pragma unroll
    for (int j = 0; j < 4; ++j) n[j] = v[j] * rms * w[d0 + j];

    float outv[4];
#pragma unroll
    for (int e = 0; e < 4; e += 2) {
      const int i0 = d0 + e, i1 = i0 + 1;
      const float f0 = exp2f(-(float)(i0 & 127) * 0.103810253f);
      const float f1 = exp2f(-(float)(i1 & 127) * 0.103810253f);
      float s0, cc0, s1, cc1;
      sincosf(p * f0, &s0, &cc0);
      sincosf(p * f1, &s1, &cc1);
      outv[e]     = n[e] * cc0 - n[e + 1] * s0;
      outv[e + 1] = n[e + 1] * cc1 + n[e] * s1;
    }
#pragma unroll
    for (int j = 0; j < 4; ++j) base[d0 + j] = (__bf16)outv[j];
  } else {
    __shared__ __bf16 tile[64][72];
    const int b   = blockIdx.x - 12288;       // 0..1023
    const int tid = threadIdx.x;
    const int tb  = (b & 63) * 64;
    const int yy  = b >> 6;                   // 0..15
    const int kvh = yy >> 2;
    const int db  = (yy & 3) * 64;
#pragma unroll
    for (int i = 0; i < 2; ++i) {
      const int s = i * 256 + tid;
      const int r = s >> 3, c = (s & 7) * 8;
      bf16x8 val = *(const bf16x8*)(qkv + (size_t)(tb + r) * 4096 + 3072 + kvh * HD + db + c);
#pragma unroll
      for (int j = 0; j < 8; ++j) tile[r][c + j] = val[j];
    }
    __syncthreads();
#pragma unroll
    for (int i = 0; i < 2; ++i) {
      const int s = i * 256 + tid;
      const int r = s >> 3, c = (s & 7) * 8;
      bf16x8 outv;
#pragma unroll
      for (int j = 0; j < 8; ++j) outv[j] = tile[c + j][r];
      *(bf16x8*)(Vt + (size_t)(kvh * HD + db + r) * SEQ + tb + c) = outv;
    }
  }
}

// ---------------------------------------------------------------------------
// Sliding-window flash attention, fixed-max softmax, async LDS staging
// (round-6 config: 256 thr, grid (64,8), 2 blocks/CU — inter-block overlap
// hides staging latency per m114; dbuf measured neutral).
// ---------------------------------------------------------------------------
__global__ __launch_bounds__(256, 2)
void attn_fwd(const __bf16* __restrict__ qkv, const __bf16* __restrict__ Vt,
              __bf16* __restrict__ Y) {
  __shared__ __bf16 Ks2[8][64][32];    // 32768 B  [k-chunk][key][dim8]
  __shared__ __bf16 Vts2[2][256][32];  // 32768 B  [key-chunk][dim][key8]
  __shared__ __bf16 Ps[4][16][72];     //  9216 B  per-wave P
  const int tid  = threadIdx.x;
  const int lane = tid & 63;
  const int wave = tid >> 6;
  const int l15  = lane & 15;
  const int l4   = lane >> 4;
  const int q0   = blockIdx.x * 64;
  const int head = blockIdx.y;
  const int kvh  = head >> 1;
  const int qw   = q0 + wave * 16;

  // Q fragments: A[m=lane&15][k=(lane>>4)*8+j]; pre-scale 1/16 (exact pow2)
  bf16x8 qf[8];
  const __bf16* qrow = qkv + (size_t)(qw + l15) * 4096 + head * HD;
#pragma unroll
  for (int ks = 0; ks < 8; ++ks) {
    bf16x8 t = *(const bf16x8*)(qrow + ks * 32 + l4 * 8);
#pragma unroll
    for (int j = 0; j < 8; ++j) t[j] = (__bf16)((float)t[j] * 0.0625f);
    qf[ks] = t;
  }

  f32x4 o[16] = {};
  float l_run[4] = {0.f, 0.f, 0.f, 0.f};

  int lo = q0 - (WIN - 1); if (lo < 0) lo = 0;
  const int kt0 = lo >> 6;
  const int kt1 = (q0 + 63) >> 6;   // uniform across the block

  for (int kt = kt0; kt <= kt1; ++kt) {
    const int kb = kt * 64;
    __syncthreads();
#pragma unroll
    for (int i = 0; i < 8; ++i) {
      const int s = i * 256 + tid;
      gload16(qkv + (size_t)(kb + ((s >> 2) & 63)) * 4096 + 2048 + kvh * HD
                  + (s >> 8) * 32 + (s & 3) * 8,
              (char*)Ks2 + (i * 256 + wave * 64) * 16);
    }
#pragma unroll
    for (int i = 0; i < 8; ++i) {
      const int s = i * 256 + tid;
      gload16(Vt + ((size_t)kvh * HD + ((s >> 2) & 255)) * SEQ + kb
                 + (s >> 10) * 32 + (s & 3) * 8,
              (char*)Vts2 + (i * 256 + wave * 64) * 16);
    }
    __syncthreads();

    // S = (Q/16) K^T
    f32x4 s_acc[4] = {};
#pragma unroll
    for (int kn = 0; kn < 4; ++kn) {
#pragma unroll
      for (int ks = 0; ks < 8; ++ks) {
        bf16x8 kf = *(const bf16x8*)&Ks2[ks][kn * 16 + l15][l4 * 8];
        s_acc[kn] = __builtin_amdgcn_mfma_f32_16x16x32_bf16(qf[ks], kf, s_acc[kn], 0, 0, 0);
      }
    }

    // fixed-max softmax: p = exp(min(s,34)-34); masked -> 0
    // (post-RMSNorm |q|=|k|=16, RoPE growth <= sqrt2 => s <= 32 provably)
#pragma unroll
    for (int reg = 0; reg < 4; ++reg) {
      const int r  = l4 * 4 + reg;
      const int qg = qw + r;
      float ps = 0.f;
#pragma unroll
      for (int kn = 0; kn < 4; ++kn) {
        const int kg = kb + kn * 16 + l15;
        const bool ok = (kg <= qg) && (kg > qg - WIN);
        const float p = ok ? __expf(fminf(s_acc[kn][reg], 34.f) - 34.f) : 0.f;
        ps += p;
        Ps[wave][r][kn * 16 + l15] = (__bf16)p;
      }
      l_run[reg] += ps;
    }

    // O += P V   (Ps per-wave; intra-wave LDS ordering needs no barrier)
#pragma unroll
    for (int ks2 = 0; ks2 < 2; ++ks2) {
      bf16x8 pf = *(const bf16x8*)&Ps[wave][l15][ks2 * 32 + l4 * 8];
#pragma unroll
      for (int dn = 0; dn < 16; ++dn) {
        bf16x8 vf = *(const bf16x8*)&Vts2[ks2][dn * 16 + l15][l4 * 8];
        o[dn] = __builtin_amdgcn_mfma_f32_16x16x32_bf16(pf, vf, o[dn], 0, 0, 0);
      }
    }
  }

  // epilogue: reduce l across the 16 lanes sharing each row, then scale
#pragma unroll
  for (int reg = 0; reg < 4; ++reg) {
#pragma unroll
    for (int off = 1; off < 16; off <<= 1)
      l_run[reg] += __shfl_xor(l_run[reg], off);
    const float inv = 1.0f / l_run[reg];
    const int q = qw + l4 * 4 + reg;
    __bf16* yrow = Y + ((size_t)q * NH + head) * HD + l15;
#pragma unroll
    for (int dn = 0; dn < 16; ++dn)
      yrow[dn * 16] = (__bf16)(o[dn][reg] * inv);
  }
}

// ---------------------------------------------------------------------------
extern "C" void kernel_launch(void* const* d_in, const int* in_sizes, int n_in,
                              void* d_out, int out_size, void* d_ws, size_t ws_size,
                              hipStream_t stream) {
  (void)in_sizes; (void)n_in; (void)out_size; (void)ws_size;
  const float* x   = (const float*)d_in[0];
  const int*   pos = (const int*)d_in[1];
  const float* Wq  = (const float*)d_in[2];
  const float* Wk  = (const float*)d_in[3];
  const float* Wv  = (const float*)d_in[4];
  const float* Wo  = (const float*)d_in[5];
  const float* qw  = (const float*)d_in[6];
  const float* kw  = (const float*)d_in[7];
  float* out = (float*)d_out;

  char* ws = (char*)d_ws;
  const size_t MB = 1024 * 1024;
  __bf16* qkv_ws = (__bf16*)(ws);             // 32 MiB  [4096][4096]
  __bf16* vt_ws  = (__bf16*)(ws + 32 * MB);   //  8 MiB  [4][256][4096]
  __bf16* y_ws   = (__bf16*)(ws + 40 * MB);   // 16 MiB  [4096][2048]
  __bf16* xb     = (__bf16*)(ws + 56 * MB);   // 16 MiB
  __bf16* wqkvb  = (__bf16*)(ws + 72 * MB);   // 16 MiB  [4096][2048]
  __bf16* wob    = (__bf16*)(ws + 88 * MB);   //  8 MiB  (total 96 MiB)

  cvt_all<<<dim3(10240), dim3(256), 0, stream>>>(x, Wq, Wk, Wv, Wo, xb, wqkvb, wob);
  gemm_bt<__bf16><<<dim3(32, 32), dim3(256), 0, stream>>>(xb, wqkvb, qkv_ws, 4096, 2048);
  norm_rope_tv<<<dim3(13312), dim3(256), 0, stream>>>(qkv_ws, vt_ws, qw, kw, pos);
  attn_fwd<<<dim3(64, 8), dim3(256), 0, stream>>>(qkv_ws, vt_ws, y_ws);
  gemm_bt<float><<<dim3(32, 16), dim3(256), 0, stream>>>(y_ws, wob, out, 2048, 2048);
}